// Round 4
// baseline (237.061 us; speedup 1.0000x reference)
//
#include <hip/hip_runtime.h>

// NodeFeatures: out = relu(x@Wu^T + bu + mask @ (x@Wv^T + bv))
// B=8, N=2048, D=128. HBM floor = 128MB mask read ~= 20.3us.
// Strategy: bf16 MFMA (16x16x32) for both GEMMs; mask(0/1) exact in bf16.

typedef __bf16 bf16x8 __attribute__((ext_vector_type(8)));
typedef __bf16 bf16x4 __attribute__((ext_vector_type(4)));
typedef float  f32x4  __attribute__((ext_vector_type(4)));

#define MFMA16(A, B, C) __builtin_amdgcn_mfma_f32_16x16x32_bf16(A, B, C, 0, 0, 0)

static __device__ __forceinline__ bf16x8 cvt8(const float* __restrict__ p) {
    float4 a = *(const float4*)p;
    float4 b = *(const float4*)(p + 4);
    bf16x8 v;
    v[0] = (__bf16)a.x; v[1] = (__bf16)a.y; v[2] = (__bf16)a.z; v[3] = (__bf16)a.w;
    v[4] = (__bf16)b.x; v[5] = (__bf16)b.y; v[6] = (__bf16)b.z; v[7] = (__bf16)b.w;
    return v;
}

// ---------------------------------------------------------------------------
// Kernel 1: Uxb[row][e] = bf16(x@Wu^T + bu); Vt[b][e][n] = bf16(x@Wv^T + bv)
// Block: 64 rows, 4 waves; wave w handles output cols [32w,32w+32) of U and V.
// A-frag: lane reads x[m0+l16][k..k+7] (f32->bf16). B-frag: W[e][k..k+7].
// D-frag (m89-verified): col = lane&15, row = (lane>>4)*4 + reg.
// ---------------------------------------------------------------------------
__global__ __launch_bounds__(256) void k1_uv(
    const float* __restrict__ x,  const float* __restrict__ Wu,
    const float* __restrict__ bu, const float* __restrict__ Wv,
    const float* __restrict__ bv,
    __bf16* __restrict__ Uxb, __bf16* __restrict__ Vt)
{
    const int tid  = threadIdx.x;
    const int wv   = tid >> 6;
    const int lane = tid & 63;
    const int l16  = lane & 15;
    const int l4   = lane >> 4;
    const int row0 = blockIdx.x * 64;   // 16384/64 = 256 blocks; stays in one batch (2048%64==0)
    const int e0   = wv * 32;

    const f32x4 zero = {0.f, 0.f, 0.f, 0.f};
    f32x4 acc[4][4];   // [m-tile][frag: U0,U1,V0,V1]
    #pragma unroll
    for (int mt = 0; mt < 4; ++mt)
        #pragma unroll
        for (int f = 0; f < 4; ++f) acc[mt][f] = zero;

    #pragma unroll
    for (int kf = 0; kf < 4; ++kf) {
        const int ko = kf * 32 + l4 * 8;
        bf16x8 af[4], bf[4];
        #pragma unroll
        for (int mt = 0; mt < 4; ++mt)
            af[mt] = cvt8(x + (size_t)(row0 + mt * 16 + l16) * 128 + ko);
        bf[0] = cvt8(Wu + (size_t)(e0 +      l16) * 128 + ko);
        bf[1] = cvt8(Wu + (size_t)(e0 + 16 + l16) * 128 + ko);
        bf[2] = cvt8(Wv + (size_t)(e0 +      l16) * 128 + ko);
        bf[3] = cvt8(Wv + (size_t)(e0 + 16 + l16) * 128 + ko);
        #pragma unroll
        for (int mt = 0; mt < 4; ++mt)
            #pragma unroll
            for (int f = 0; f < 4; ++f)
                acc[mt][f] = MFMA16(af[mt], bf[f], acc[mt][f]);
    }

    const int bidx = row0 >> 11;   // batch index
    #pragma unroll
    for (int f = 0; f < 4; ++f) {
        const int e    = e0 + (f & 1) * 16 + l16;
        const bool isV = (f >= 2);
        const float bias = isV ? bv[e] : bu[e];
        #pragma unroll
        for (int mt = 0; mt < 4; ++mt) {
            if (!isV) {
                #pragma unroll
                for (int r = 0; r < 4; ++r) {
                    const int row = row0 + mt * 16 + l4 * 4 + r;
                    Uxb[(size_t)row * 128 + e] = (__bf16)(acc[mt][f][r] + bias);
                }
            } else {
                const int nbase = (row0 & 2047) + mt * 16 + l4 * 4;  // 4 consecutive n
                bf16x4 pk;
                #pragma unroll
                for (int r = 0; r < 4; ++r) pk[r] = (__bf16)(acc[mt][f][r] + bias);
                *(bf16x4*)(Vt + ((size_t)bidx * 128 + e) * 2048 + nbase) = pk;
            }
        }
    }
}

// ---------------------------------------------------------------------------
// Kernel 2: out[b,i,:] = relu(Uxb[b,i,:] + sum_j mask[b,i,j] * Vx[b,j,:])
// Grid 512 (XCD-swizzled: batch b -> one XCD, keeps Vt[b] (512KB) L2-hot).
// Block: BM=32 rows x full D=128, BK=64; 4 waves, wave w = cols [32w,32w+32).
// Mask tile: f32 global -> regs (prefetched one step ahead) -> bf16 ->
// XOR-swizzled LDS [32 rows][8 slots of 16B], slot ^= (row&7): 2-way (free).
// ---------------------------------------------------------------------------
__global__ __launch_bounds__(256) void k2_agg(
    const float* __restrict__ mask,
    const __bf16* __restrict__ Vt,
    const __bf16* __restrict__ Uxb,
    float* __restrict__ out)
{
    __shared__ bf16x8 smem[32 * 8];   // 4KB, swizzled

    const int bid = blockIdx.x;               // 0..511
    const int lb  = (bid & 7) * 64 + (bid >> 3);  // bijective XCD swizzle (512 = 8*64)
    const int b   = lb >> 6;                  // batch
    const int m0  = (lb & 63) * 32;           // row tile within batch

    const int tid  = threadIdx.x;
    const int wv   = tid >> 6;
    const int lane = tid & 63;
    const int l16  = lane & 15;
    const int l4   = lane >> 4;

    const int sr = tid >> 3;    // staging row 0..31
    const int ss = tid & 7;     // staging slot 0..7 (8 f32 each)

    const float*  mrow = mask + ((size_t)b * 2048 + m0 + sr) * 2048 + ss * 8;
    const __bf16* VtB  = Vt + (size_t)b * 128 * 2048;

    const f32x4 zero = {0.f, 0.f, 0.f, 0.f};
    f32x4 acc[2][2];
    acc[0][0] = zero; acc[0][1] = zero; acc[1][0] = zero; acc[1][1] = zero;

    // prologue: prefetch mask tile 0 into regs
    float4 p0 = *(const float4*)(mrow);
    float4 p1 = *(const float4*)(mrow + 4);

    for (int ks = 0; ks < 32; ++ks) {
        {   // regs -> bf16 -> swizzled LDS
            bf16x8 v;
            v[0] = (__bf16)p0.x; v[1] = (__bf16)p0.y; v[2] = (__bf16)p0.z; v[3] = (__bf16)p0.w;
            v[4] = (__bf16)p1.x; v[5] = (__bf16)p1.y; v[6] = (__bf16)p1.z; v[7] = (__bf16)p1.w;
            smem[sr * 8 + (ss ^ (sr & 7))] = v;
        }
        __syncthreads();
        if (ks + 1 < 32) {      // issue next tile's loads; latency hides under MFMA
            const float* mp = mrow + (ks + 1) * 64;
            p0 = *(const float4*)(mp);
            p1 = *(const float4*)(mp + 4);
        }
        #pragma unroll
        for (int kf = 0; kf < 2; ++kf) {
            bf16x8 afr[2];
            #pragma unroll
            for (int mf = 0; mf < 2; ++mf) {
                const int m = mf * 16 + l16;
                afr[mf] = smem[m * 8 + ((kf * 4 + l4) ^ (m & 7))];
            }
            #pragma unroll
            for (int nf = 0; nf < 2; ++nf) {
                const __bf16* vp = VtB + (size_t)(wv * 32 + nf * 16 + l16) * 2048
                                       + ks * 64 + kf * 32 + l4 * 8;
                bf16x8 bfv = *(const bf16x8*)vp;   // 16B, L2-hot
                #pragma unroll
                for (int mf = 0; mf < 2; ++mf)
                    acc[mf][nf] = MFMA16(afr[mf], bfv, acc[mf][nf]);
            }
        }
        __syncthreads();
    }

    // epilogue: out = relu(acc + Ux)
    const size_t rowbase = (size_t)b * 2048 + m0;
    #pragma unroll
    for (int mf = 0; mf < 2; ++mf)
        #pragma unroll
        for (int nf = 0; nf < 2; ++nf) {
            const int e = wv * 32 + nf * 16 + l16;
            #pragma unroll
            for (int r = 0; r < 4; ++r) {
                const size_t row = rowbase + mf * 16 + l4 * 4 + r;
                const float v = acc[mf][nf][r] + (float)Uxb[row * 128 + e];
                out[row * 128 + e] = v > 0.f ? v : 0.f;
            }
        }
}

// ---------------------------------------------------------------------------
extern "C" void kernel_launch(void* const* d_in, const int* in_sizes, int n_in,
                              void* d_out, int out_size, void* d_ws, size_t ws_size,
                              hipStream_t stream) {
    (void)in_sizes; (void)n_in; (void)out_size; (void)ws_size;
    const float* x    = (const float*)d_in[0];   // [8][2048][128]
    const float* mask = (const float*)d_in[1];   // [8][2048][2048]
    const float* Wu   = (const float*)d_in[2];   // [128][128]
    const float* bu   = (const float*)d_in[3];   // [128]
    const float* Wv   = (const float*)d_in[4];   // [128][128]
    const float* bv   = (const float*)d_in[5];   // [128]
    float* out        = (float*)d_out;           // [8][2048][128] f32

    __bf16* Vt  = (__bf16*)d_ws;                 // [8][128][2048] bf16 (4MB)
    __bf16* Uxb = Vt + (size_t)8 * 128 * 2048;   // [16384][128]  bf16 (4MB)

    hipLaunchKernelGGL(k1_uv, dim3(256), dim3(256), 0, stream, x, Wu, bu, Wv, bv, Uxb, Vt);
    hipLaunchKernelGGL(k2_agg, dim3(512), dim3(256), 0, stream, mask, Vt, Uxb, out);
}

// Round 5
// 232.777 us; speedup vs baseline: 1.0184x; 1.0184x over previous
//
#include <hip/hip_runtime.h>

// NodeFeatures: out = relu(x@Wu^T + bu + mask @ (x@Wv^T + bv))
// B=8, N=2048, D=128. HBM floor = 128MB mask read ~= 20us @ 6.8TB/s.
// R4: passed, absmax 1.0. Headline dur 237us but top-5 dispatches are all
// 512MB harness poison-fills (~78us each, ~234us total) -> kernels likely
// < 77us each and possibly invisible in the headline. R5: single-barrier
// double-buffered k2 with 2-phase prefetch distance; decision rule in journal.

typedef __bf16 bf16x8 __attribute__((ext_vector_type(8)));
typedef __bf16 bf16x4 __attribute__((ext_vector_type(4)));
typedef float  f32x4  __attribute__((ext_vector_type(4)));

#define MFMA16(A, B, C) __builtin_amdgcn_mfma_f32_16x16x32_bf16(A, B, C, 0, 0, 0)

static __device__ __forceinline__ bf16x8 cvt8(const float* __restrict__ p) {
    float4 a = *(const float4*)p;
    float4 b = *(const float4*)(p + 4);
    bf16x8 v;
    v[0] = (__bf16)a.x; v[1] = (__bf16)a.y; v[2] = (__bf16)a.z; v[3] = (__bf16)a.w;
    v[4] = (__bf16)b.x; v[5] = (__bf16)b.y; v[6] = (__bf16)b.z; v[7] = (__bf16)b.w;
    return v;
}

static __device__ __forceinline__ bf16x8 pack8(const float4 a, const float4 b) {
    bf16x8 v;
    v[0] = (__bf16)a.x; v[1] = (__bf16)a.y; v[2] = (__bf16)a.z; v[3] = (__bf16)a.w;
    v[4] = (__bf16)b.x; v[5] = (__bf16)b.y; v[6] = (__bf16)b.z; v[7] = (__bf16)b.w;
    return v;
}

// ---------------------------------------------------------------------------
// Kernel 1 (unchanged from R4): Uxb = bf16(x@Wu^T+bu); Vt[b][e][n] = bf16(x@Wv^T+bv)
// D-frag (m89-verified): col = lane&15, row = (lane>>4)*4 + reg.
// ---------------------------------------------------------------------------
__global__ __launch_bounds__(256) void k1_uv(
    const float* __restrict__ x,  const float* __restrict__ Wu,
    const float* __restrict__ bu, const float* __restrict__ Wv,
    const float* __restrict__ bv,
    __bf16* __restrict__ Uxb, __bf16* __restrict__ Vt)
{
    const int tid  = threadIdx.x;
    const int wv   = tid >> 6;
    const int lane = tid & 63;
    const int l16  = lane & 15;
    const int l4   = lane >> 4;
    const int row0 = blockIdx.x * 64;
    const int e0   = wv * 32;

    const f32x4 zero = {0.f, 0.f, 0.f, 0.f};
    f32x4 acc[4][4];
    #pragma unroll
    for (int mt = 0; mt < 4; ++mt)
        #pragma unroll
        for (int f = 0; f < 4; ++f) acc[mt][f] = zero;

    #pragma unroll
    for (int kf = 0; kf < 4; ++kf) {
        const int ko = kf * 32 + l4 * 8;
        bf16x8 af[4], bf[4];
        #pragma unroll
        for (int mt = 0; mt < 4; ++mt)
            af[mt] = cvt8(x + (size_t)(row0 + mt * 16 + l16) * 128 + ko);
        bf[0] = cvt8(Wu + (size_t)(e0 +      l16) * 128 + ko);
        bf[1] = cvt8(Wu + (size_t)(e0 + 16 + l16) * 128 + ko);
        bf[2] = cvt8(Wv + (size_t)(e0 +      l16) * 128 + ko);
        bf[3] = cvt8(Wv + (size_t)(e0 + 16 + l16) * 128 + ko);
        #pragma unroll
        for (int mt = 0; mt < 4; ++mt)
            #pragma unroll
            for (int f = 0; f < 4; ++f)
                acc[mt][f] = MFMA16(af[mt], bf[f], acc[mt][f]);
    }

    const int bidx = row0 >> 11;
    #pragma unroll
    for (int f = 0; f < 4; ++f) {
        const int e    = e0 + (f & 1) * 16 + l16;
        const bool isV = (f >= 2);
        const float bias = isV ? bv[e] : bu[e];
        #pragma unroll
        for (int mt = 0; mt < 4; ++mt) {
            if (!isV) {
                #pragma unroll
                for (int r = 0; r < 4; ++r) {
                    const int row = row0 + mt * 16 + l4 * 4 + r;
                    Uxb[(size_t)row * 128 + e] = (__bf16)(acc[mt][f][r] + bias);
                }
            } else {
                const int nbase = (row0 & 2047) + mt * 16 + l4 * 4;
                bf16x4 pk;
                #pragma unroll
                for (int r = 0; r < 4; ++r) pk[r] = (__bf16)(acc[mt][f][r] + bias);
                *(bf16x4*)(Vt + ((size_t)bidx * 128 + e) * 2048 + nbase) = pk;
            }
        }
    }
}

// ---------------------------------------------------------------------------
// Kernel 2 (R5): single-barrier double-buffered pipeline.
// Per K-step (BK=64): { prefetch mask tile (regs, ping-pong A/B) || MFMA from
// LDS buf[cur] || ds_write buf[cur^1] <- regs } then ONE __syncthreads().
// Load->ds_write distance ~ 1 full compute phase + barrier + compute phase.
// XOR swizzle slot^=(row&7) on write and read: 2-way bank alias (free, m136).
// ---------------------------------------------------------------------------
__global__ __launch_bounds__(256) void k2_agg(
    const float* __restrict__ mask,
    const __bf16* __restrict__ Vt,
    const __bf16* __restrict__ Uxb,
    float* __restrict__ out)
{
    __shared__ bf16x8 smem[2][32 * 8];   // 2 x 4KB, swizzled

    const int bid = blockIdx.x;                   // 0..511
    const int lb  = (bid & 7) * 64 + (bid >> 3);  // bijective XCD swizzle (512 = 8*64)
    const int b   = lb >> 6;
    const int m0  = (lb & 63) * 32;

    const int tid  = threadIdx.x;
    const int wv   = tid >> 6;
    const int lane = tid & 63;
    const int l16  = lane & 15;
    const int l4   = lane >> 4;

    const int sr = tid >> 3;               // staging row 0..31
    const int ss = tid & 7;                // staging slot 0..7
    const int sw = sr * 8 + (ss ^ (sr & 7));   // swizzled LDS index

    const float*  mrow = mask + ((size_t)b * 2048 + m0 + sr) * 2048 + ss * 8;
    const __bf16* VtB  = Vt + (size_t)b * 128 * 2048;

    const f32x4 zero = {0.f, 0.f, 0.f, 0.f};
    f32x4 acc[2][2];
    acc[0][0] = zero; acc[0][1] = zero; acc[1][0] = zero; acc[1][1] = zero;

#define COMPUTE(BUF, KS)                                                      \
    { _Pragma("unroll")                                                       \
      for (int kf = 0; kf < 2; ++kf) {                                        \
        bf16x8 afr[2];                                                        \
        _Pragma("unroll")                                                     \
        for (int mf = 0; mf < 2; ++mf) {                                      \
          const int m = mf * 16 + l16;                                        \
          afr[mf] = smem[BUF][m * 8 + ((kf * 4 + l4) ^ (m & 7))];             \
        }                                                                     \
        _Pragma("unroll")                                                     \
        for (int nf = 0; nf < 2; ++nf) {                                      \
          const __bf16* vp = VtB + (size_t)(wv * 32 + nf * 16 + l16) * 2048   \
                                 + (KS) * 64 + kf * 32 + l4 * 8;              \
          bf16x8 bfv = *(const bf16x8*)vp;                                    \
          _Pragma("unroll")                                                   \
          for (int mf = 0; mf < 2; ++mf)                                      \
            acc[mf][nf] = MFMA16(afr[mf], bfv, acc[mf][nf]);                  \
        }                                                                     \
      }                                                                       \
    }

    // prologue: tile0 -> buf0 (blocking); tile1 -> regs B (in flight)
    float4 a0 = *(const float4*)(mrow);
    float4 a1 = *(const float4*)(mrow + 4);
    smem[0][sw] = pack8(a0, a1);
    float4 b0 = *(const float4*)(mrow + 64);
    float4 b1 = *(const float4*)(mrow + 68);
    __syncthreads();

    #pragma unroll 2
    for (int t = 0; t < 16; ++t) {
        const int ks = 2 * t;
        // half 1: compute tile ks from buf0; stage tile ks+1 into buf1;
        //         issue loads for tile ks+2 -> regs A
        if (ks + 2 < 32) {
            const float* mp = mrow + (size_t)(ks + 2) * 64;
            a0 = *(const float4*)(mp);
            a1 = *(const float4*)(mp + 4);
        }
        COMPUTE(0, ks)
        smem[1][sw] = pack8(b0, b1);      // waits on B issued last iteration
        __syncthreads();
        // half 2: compute tile ks+1 from buf1; stage tile ks+2 into buf0;
        //         issue loads for tile ks+3 -> regs B
        if (ks + 3 < 32) {
            const float* mp = mrow + (size_t)(ks + 3) * 64;
            b0 = *(const float4*)(mp);
            b1 = *(const float4*)(mp + 4);
        }
        COMPUTE(1, ks + 1)
        if (ks + 2 < 32) smem[0][sw] = pack8(a0, a1);  // A: issued ~2 phases ago
        __syncthreads();
    }
#undef COMPUTE

    // epilogue: out = relu(acc + Ux)
    const size_t rowbase = (size_t)b * 2048 + m0;
    #pragma unroll
    for (int mf = 0; mf < 2; ++mf)
        #pragma unroll
        for (int nf = 0; nf < 2; ++nf) {
            const int e = wv * 32 + nf * 16 + l16;
            #pragma unroll
            for (int r = 0; r < 4; ++r) {
                const size_t row = rowbase + mf * 16 + l4 * 4 + r;
                const float v = acc[mf][nf][r] + (float)Uxb[row * 128 + e];
                out[row * 128 + e] = v > 0.f ? v : 0.f;
            }
        }
}

// ---------------------------------------------------------------------------
extern "C" void kernel_launch(void* const* d_in, const int* in_sizes, int n_in,
                              void* d_out, int out_size, void* d_ws, size_t ws_size,
                              hipStream_t stream) {
    (void)in_sizes; (void)n_in; (void)out_size; (void)ws_size;
    const float* x    = (const float*)d_in[0];   // [8][2048][128]
    const float* mask = (const float*)d_in[1];   // [8][2048][2048]
    const float* Wu   = (const float*)d_in[2];   // [128][128]
    const float* bu   = (const float*)d_in[3];   // [128]
    const float* Wv   = (const float*)d_in[4];   // [128][128]
    const float* bv   = (const float*)d_in[5];   // [128]
    float* out        = (float*)d_out;           // [8][2048][128] f32

    __bf16* Vt  = (__bf16*)d_ws;                 // [8][128][2048] bf16 (4MB)
    __bf16* Uxb = Vt + (size_t)8 * 128 * 2048;   // [16384][128]  bf16 (4MB)

    hipLaunchKernelGGL(k1_uv, dim3(256), dim3(256), 0, stream, x, Wu, bu, Wv, bv, Uxb, Vt);
    hipLaunchKernelGGL(k2_agg, dim3(512), dim3(256), 0, stream, mask, Vt, Uxb, out);
}